// Round 9
// baseline (476.558 us; speedup 1.0000x reference)
//
#include <hip/hip_runtime.h>
#include <stdint.h>

typedef int v4i __attribute__((ext_vector_type(4)));

#define K_DIM 4096
#define TPB_Q 256
#define BM 256
#define BN 256
#define BKB 128                     // K-bytes per tile
#define NT (K_DIM / BKB)            // 32 K-tiles
#define TILE_BYTES (256 * BKB)      // 32 KiB A tile

__device__ __forceinline__ void load_lds16(const void* g, void* l) {
  __builtin_amdgcn_global_load_lds(
      (const __attribute__((address_space(1))) void*)g,
      (__attribute__((address_space(3))) void*)l, 16, 0, 0);
}

// ---------------- per-row symmetric int8 quant (BW-bound, unchanged) --------
__global__ __launch_bounds__(TPB_Q) void quant_rows_kernel(
    const float* __restrict__ x, signed char* __restrict__ q,
    float* __restrict__ scales) {
  const int row = blockIdx.x;
  const float4* xr = (const float4*)(x + (size_t)row * K_DIM);
  float4 v[4];
  float m = 0.0f;
#pragma unroll
  for (int i = 0; i < 4; ++i) {
    v[i] = xr[threadIdx.x + i * TPB_Q];
    m = fmaxf(m, fmaxf(fmaxf(fabsf(v[i].x), fabsf(v[i].y)),
                       fmaxf(fabsf(v[i].z), fabsf(v[i].w))));
  }
#pragma unroll
  for (int off = 32; off > 0; off >>= 1) m = fmaxf(m, __shfl_down(m, off));
  __shared__ float red[TPB_Q / 64];
  if ((threadIdx.x & 63) == 0) red[threadIdx.x >> 6] = m;
  __syncthreads();
  m = fmaxf(fmaxf(red[0], red[1]), fmaxf(red[2], red[3]));
  const float scale = fmaxf(m / 127.0f, 1e-8f);
  if (threadIdx.x == 0) scales[row] = scale;
  uint32_t* qr = (uint32_t*)(q + (size_t)row * K_DIM);
#pragma unroll
  for (int i = 0; i < 4; ++i) {
    const float4 t = v[i];
    const int a0 = (int)fminf(fmaxf(rintf(t.x / scale), -128.0f), 127.0f);
    const int a1 = (int)fminf(fmaxf(rintf(t.y / scale), -128.0f), 127.0f);
    const int a2 = (int)fminf(fmaxf(rintf(t.z / scale), -128.0f), 127.0f);
    const int a3 = (int)fminf(fmaxf(rintf(t.w / scale), -128.0f), 127.0f);
    const uint32_t p = (uint32_t)(a0 & 255) | ((uint32_t)(a1 & 255) << 8) |
                       ((uint32_t)(a2 & 255) << 16) | ((uint32_t)(a3 & 255) << 24);
    qr[threadIdx.x + i * TPB_Q] = p;
  }
}

// ---------------- 256x256 i8 GEMM: A via LDS, B global->reg ----------------
// 8 waves: wm=wave>>2 (2), wn=wave&3 (4). Per-wave C: 128x64 = acc[8][4].
// A: LDS full-tile double buffer (2 x 32 KiB), XOR-swizzled 16B chunks
//    (phys_chunk = logical ^ (row&7)); staged with 4 global_load_lds/tile.
// B: registers, loaded straight from global (layout [N,K] matches fragment:
//    lane reads 16B at row wn*64+nj*16+l16, k = T*128 + ks*64 + lhi*16),
//    double-buffered across tiles via named bcur/bnxt (manual 2x unroll).
// Per K-tile (free-run, 1 barrier): issue 16 A ds_reads (4 pinned groups),
// prefetch B(T+1) to regs, stage A(T+1); MFMA pair-clusters gated by
// lgkmcnt(12)/(8)/(4)/(0); vmcnt(0)+s_barrier at boundary (covers own A
// stage and B prefetch; both had the whole MFMA span to land).
// XCD swizzle: grid 32r x 16c; XCD k owns rows[8*(k>>1),+8) x cols[8*(k&1),+8).
__global__ __launch_bounds__(512, 2) void gemm_i8_kernel(
    const signed char* __restrict__ qA, const signed char* __restrict__ qB,
    const float* __restrict__ sA, const float* __restrict__ sB,
    float* __restrict__ C, int M, int N, int K) {
  __shared__ __align__(16) signed char As[2 * TILE_BYTES];  // 64 KiB

  const int tid = threadIdx.x;
  const int wave = tid >> 6, lane = tid & 63;
  const int l16 = lane & 15, lhi = lane >> 4;
  const int wm = wave >> 2, wn = wave & 3;

  // XCD-chunked 2-D swizzle (bijective; 512 blocks, 8 XCDs, o%8 = XCD)
  const int o = blockIdx.x + blockIdx.y * gridDim.x;
  const int xcd = o & 7, slot = o >> 3;
  const int rb = ((xcd >> 1) << 3) + (slot >> 3);  // grid row 0..31
  const int cb = ((xcd & 1) << 3) + (slot & 7);    // grid col 0..15
  const int m0 = rb * BM, n0 = cb * BN;

  const signed char* Abase = qA + (size_t)m0 * K;
  const signed char* Bbase = qB + (size_t)n0 * K;

  // A staging: tile = 2048 x 16B chunks; thread d = s*512+tid, s=0..3.
  // dest linear (wave-uniform base + lane*16); source inverse-swizzled.
  int soff[4], sdst[4];
#pragma unroll
  for (int s = 0; s < 4; ++s) {
    const int d = s * 512 + tid;
    const int r = d >> 3;
    const int c = (d & 7) ^ (r & 7);
    soff[s] = r * K + c * 16;
    sdst[s] = s * 8192 + wave * 1024;
  }

#define STAGE_A(T_)                                                         \
  do {                                                                      \
    _Pragma("unroll") for (int s = 0; s < 4; ++s)                           \
        load_lds16(Abase + (size_t)(T_)*BKB + soff[s],                      \
                   As + ((T_)&1) * TILE_BYTES + sdst[s]);                   \
  } while (0)

  // swizzled A ds_read offsets (chunk = ks*4+lhi, row&7 = l16&7)
  int axor[2];
#pragma unroll
  for (int ks = 0; ks < 2; ++ks)
    axor[ks] = (((ks * 4 + lhi) ^ (l16 & 7)) << 4);
  const int aoff = wm * 16384 + l16 * 128;  // + mi*2048

  // B global fragment byte-offsets (per lane), + T*BKB per tile
  int bgo[4][2];
#pragma unroll
  for (int nj = 0; nj < 4; ++nj)
#pragma unroll
    for (int ks = 0; ks < 2; ++ks)
      bgo[nj][ks] = (wn * 64 + nj * 16 + l16) * K + ks * 64 + lhi * 16;

  const v4i vz = {0, 0, 0, 0};
  v4i acc[8][4];
#pragma unroll
  for (int i = 0; i < 8; ++i)
#pragma unroll
    for (int j = 0; j < 4; ++j) acc[i][j] = vz;

  v4i bcur[4][2], bnxt[4][2];

  // prologue: B(0) -> bcur, stage A(0), drain, sync.
#pragma unroll
  for (int nj = 0; nj < 4; ++nj)
#pragma unroll
    for (int ks = 0; ks < 2; ++ks)
      bcur[nj][ks] = *(const v4i*)(Bbase + bgo[nj][ks]);
  STAGE_A(0);
  asm volatile("s_waitcnt vmcnt(0)" ::: "memory");
  __builtin_amdgcn_s_barrier();

#define MFMA_PAIR(p0_, p1_, B_)                                              \
  do {                                                                       \
    _Pragma("unroll") for (int ks = 0; ks < 2; ++ks) {                       \
      _Pragma("unroll") for (int nj = 0; nj < 4; ++nj)                       \
          acc[p0_][nj] = __builtin_amdgcn_mfma_i32_16x16x64_i8(              \
              a[p0_][ks], B_[nj][ks], acc[p0_][nj], 0, 0, 0);                \
      _Pragma("unroll") for (int nj = 0; nj < 4; ++nj)                       \
          acc[p1_][nj] = __builtin_amdgcn_mfma_i32_16x16x64_i8(              \
              a[p1_][ks], B_[nj][ks], acc[p1_][nj], 0, 0, 0);                \
    }                                                                        \
  } while (0)

#define LGKM_GATE(n_)                                       \
  do {                                                      \
    asm volatile("s_waitcnt lgkmcnt(" #n_ ")" ::: "memory");\
    __builtin_amdgcn_sched_barrier(0);                      \
  } while (0)

#define TILE_BODY(T_, BC_, BN_)                                              \
  {                                                                          \
    const signed char* Ar = As + ((T_) & 1) * TILE_BYTES;                    \
    v4i a[8][2];                                                             \
    _Pragma("unroll") for (int mi = 0; mi < 2; ++mi)                         \
      _Pragma("unroll") for (int ks = 0; ks < 2; ++ks)                       \
        a[mi][ks] = *(const v4i*)(Ar + aoff + mi * 2048 + axor[ks]);         \
    __builtin_amdgcn_sched_barrier(0);                                       \
    _Pragma("unroll") for (int mi = 2; mi < 4; ++mi)                         \
      _Pragma("unroll") for (int ks = 0; ks < 2; ++ks)                       \
        a[mi][ks] = *(const v4i*)(Ar + aoff + mi * 2048 + axor[ks]);         \
    __builtin_amdgcn_sched_barrier(0);                                       \
    _Pragma("unroll") for (int mi = 4; mi < 6; ++mi)                         \
      _Pragma("unroll") for (int ks = 0; ks < 2; ++ks)                       \
        a[mi][ks] = *(const v4i*)(Ar + aoff + mi * 2048 + axor[ks]);         \
    __builtin_amdgcn_sched_barrier(0);                                       \
    _Pragma("unroll") for (int mi = 6; mi < 8; ++mi)                         \
      _Pragma("unroll") for (int ks = 0; ks < 2; ++ks)                       \
        a[mi][ks] = *(const v4i*)(Ar + aoff + mi * 2048 + axor[ks]);         \
    __builtin_amdgcn_sched_barrier(0);                                       \
    {                                                                        \
      const int Tn_ = ((T_) + 1 < NT) ? (T_) + 1 : (T_);                     \
      const signed char* Bp = Bbase + (size_t)Tn_ * BKB;                     \
      _Pragma("unroll") for (int nj = 0; nj < 4; ++nj)                       \
        _Pragma("unroll") for (int ks = 0; ks < 2; ++ks)                     \
          BN_[nj][ks] = *(const v4i*)(Bp + bgo[nj][ks]);                     \
    }                                                                        \
    if ((T_) + 1 < NT) STAGE_A((T_) + 1);                                    \
    LGKM_GATE(12);                                                           \
    __builtin_amdgcn_s_setprio(1);                                           \
    MFMA_PAIR(0, 1, BC_);                                                    \
    __builtin_amdgcn_s_setprio(0);                                           \
    LGKM_GATE(8);                                                            \
    __builtin_amdgcn_s_setprio(1);                                           \
    MFMA_PAIR(2, 3, BC_);                                                    \
    __builtin_amdgcn_s_setprio(0);                                           \
    LGKM_GATE(4);                                                            \
    __builtin_amdgcn_s_setprio(1);                                           \
    MFMA_PAIR(4, 5, BC_);                                                    \
    __builtin_amdgcn_s_setprio(0);                                           \
    LGKM_GATE(0);                                                            \
    __builtin_amdgcn_s_setprio(1);                                           \
    MFMA_PAIR(6, 7, BC_);                                                    \
    __builtin_amdgcn_s_setprio(0);                                           \
    asm volatile("s_waitcnt vmcnt(0)" ::: "memory");                         \
    __builtin_amdgcn_s_barrier();                                            \
  }

  for (int T = 0; T < NT; T += 2) {
    TILE_BODY(T, bcur, bnxt);
    TILE_BODY(T + 1, bnxt, bcur);
  }

  // epilogue: C/D layout col = lane&15, row = (lane>>4)*4 + reg
  float sbv[4];
#pragma unroll
  for (int nj = 0; nj < 4; ++nj) sbv[nj] = sB[n0 + wn * 64 + nj * 16 + l16];
#pragma unroll
  for (int mi = 0; mi < 8; ++mi) {
#pragma unroll
    for (int r = 0; r < 4; ++r) {
      const int row = m0 + wm * 128 + mi * 16 + lhi * 4 + r;
      const float sav = sA[row];
      float* crow = C + (size_t)row * N + (n0 + wn * 64 + l16);
#pragma unroll
      for (int nj = 0; nj < 4; ++nj)
        crow[nj * 16] = (float)acc[mi][nj][r] * sav * sbv[nj];
    }
  }
}

extern "C" void kernel_launch(void* const* d_in, const int* in_sizes, int n_in,
                              void* d_out, int out_size, void* d_ws, size_t ws_size,
                              hipStream_t stream) {
  const float* A = (const float*)d_in[0];
  const float* B = (const float*)d_in[1];
  float* C = (float*)d_out;
  const int K = K_DIM;
  const int M = in_sizes[0] / K;  // 8192
  const int N = in_sizes[1] / K;  // 4096

  signed char* qA = (signed char*)d_ws;
  signed char* qB = qA + (size_t)M * K;
  float* sA = (float*)(qB + (size_t)N * K);
  float* sB = sA + M;

  quant_rows_kernel<<<M, TPB_Q, 0, stream>>>(A, qA, sA);
  quant_rows_kernel<<<N, TPB_Q, 0, stream>>>(B, qB, sB);

  dim3 grid(N / BN, M / BM);
  gemm_i8_kernel<<<grid, 512, 0, stream>>>(qA, qB, sA, sB, C, M, N, K);
}

// Round 10
// 182.419 us; speedup vs baseline: 2.6124x; 2.6124x over previous
//
#include <hip/hip_runtime.h>
#include <stdint.h>

typedef int v4i __attribute__((ext_vector_type(4)));

#define K_DIM 4096
#define TPB_Q 256
#define BM 256
#define BN 256
#define BKB 128                     // K-bytes per tile
#define NT (K_DIM / BKB)            // 32 K-tiles
#define TILE_BYTES (256 * BKB)      // 32 KiB per operand tile

__device__ __forceinline__ void load_lds16(const void* g, void* l) {
  __builtin_amdgcn_global_load_lds(
      (const __attribute__((address_space(1))) void*)g,
      (__attribute__((address_space(3))) void*)l, 16, 0, 0);
}

// ---------------- per-row symmetric int8 quant (BW-bound, unchanged) --------
__global__ __launch_bounds__(TPB_Q) void quant_rows_kernel(
    const float* __restrict__ x, signed char* __restrict__ q,
    float* __restrict__ scales) {
  const int row = blockIdx.x;
  const float4* xr = (const float4*)(x + (size_t)row * K_DIM);
  float4 v[4];
  float m = 0.0f;
#pragma unroll
  for (int i = 0; i < 4; ++i) {
    v[i] = xr[threadIdx.x + i * TPB_Q];
    m = fmaxf(m, fmaxf(fmaxf(fabsf(v[i].x), fabsf(v[i].y)),
                       fmaxf(fabsf(v[i].z), fabsf(v[i].w))));
  }
#pragma unroll
  for (int off = 32; off > 0; off >>= 1) m = fmaxf(m, __shfl_down(m, off));
  __shared__ float red[TPB_Q / 64];
  if ((threadIdx.x & 63) == 0) red[threadIdx.x >> 6] = m;
  __syncthreads();
  m = fmaxf(fmaxf(red[0], red[1]), fmaxf(red[2], red[3]));
  const float scale = fmaxf(m / 127.0f, 1e-8f);
  if (threadIdx.x == 0) scales[row] = scale;
  uint32_t* qr = (uint32_t*)(q + (size_t)row * K_DIM);
#pragma unroll
  for (int i = 0; i < 4; ++i) {
    const float4 t = v[i];
    const int a0 = (int)fminf(fmaxf(rintf(t.x / scale), -128.0f), 127.0f);
    const int a1 = (int)fminf(fmaxf(rintf(t.y / scale), -128.0f), 127.0f);
    const int a2 = (int)fminf(fmaxf(rintf(t.z / scale), -128.0f), 127.0f);
    const int a3 = (int)fminf(fmaxf(rintf(t.w / scale), -128.0f), 127.0f);
    const uint32_t p = (uint32_t)(a0 & 255) | ((uint32_t)(a1 & 255) << 8) |
                       ((uint32_t)(a2 & 255) << 16) | ((uint32_t)(a3 & 255) << 24);
    qr[threadIdx.x + i * TPB_Q] = p;
  }
}

// ---------------- 256x256 i8 GEMM, ks-split cross-barrier pipeline ---------
// 8 waves: wm (2) x wn (4); per-wave C 128x64 = acc[8][4] (128 AGPRs).
// Fragments split by K-half: S0 = {a0[8], b0[4]} (ks=0), S1 = {ks=1} —
// 96 arch VGPRs total, same as R8 (NO new live sets; R9's spill lesson).
// LDS: A,B full-tile double buffers (4 x 32 KiB = 128 KiB), 16B-chunk XOR
// swizzle (phys = logical ^ (row&7)); staged via global_load_lds.
// Steady-state tile T (2 barriers, all gates on half-tile-old reads):
//   top:  issue S1(T) reads (12 ds); issue stage(T+1) (8 gload_lds)
//         LGKM(12) -> S0(T) done (prefetched mid-T-1);  ks0 MFMA x32
//   mid:  vmcnt(0) (stage(T+1) landed) ; s_barrier
//         issue S0(T+1) reads (12 ds) ; LGKM(12) -> S1(T) done; ks1 MFMA x32
//   end:  s_barrier  (all waves' reads of buf[T] done -> stage(T+2) safe)
// Hazards: stage(T+1) WAR on buf[(T+1)&1] fenced by T-1 ks1-gate + boundary
// barrier; S0(T+1) RAW on stage(T+1) fenced by mid vmcnt(0)+barrier.
// XCD swizzle: grid 32r x 16c; XCD k owns rows[8*(k>>1),+8) x cols[8*(k&1),+8).
__global__ __launch_bounds__(512, 2) void gemm_i8_kernel(
    const signed char* __restrict__ qA, const signed char* __restrict__ qB,
    const float* __restrict__ sA, const float* __restrict__ sB,
    float* __restrict__ C, int M, int N, int K) {
  __shared__ __align__(16) signed char As[2 * TILE_BYTES];  // 64 KiB
  __shared__ __align__(16) signed char Bs[2 * TILE_BYTES];  // 64 KiB

  const int tid = threadIdx.x;
  const int wave = tid >> 6, lane = tid & 63;
  const int l16 = lane & 15, lhi = lane >> 4;
  const int wm = wave >> 2, wn = wave & 3;

  // XCD-chunked 2-D swizzle (bijective; 512 blocks, 8 XCDs, o%8 = XCD)
  const int o = blockIdx.x + blockIdx.y * gridDim.x;
  const int xcd = o & 7, slot = o >> 3;
  const int rb = ((xcd >> 1) << 3) + (slot >> 3);  // grid row 0..31
  const int cb = ((xcd & 1) << 3) + (slot & 7);    // grid col 0..15
  const int m0 = rb * BM, n0 = cb * BN;

  const signed char* Abase = qA + (size_t)m0 * K;
  const signed char* Bbase = qB + (size_t)n0 * K;

  // staging: tile = 2048 x 16B chunks; thread d = s*512+tid, s=0..3.
  // dest linear (wave-uniform base + lane*16); source inverse-swizzled.
  int soff[4], sdst[4];
#pragma unroll
  for (int s = 0; s < 4; ++s) {
    const int d = s * 512 + tid;
    const int r = d >> 3;
    const int c = (d & 7) ^ (r & 7);
    soff[s] = r * K + c * 16;
    sdst[s] = s * 8192 + wave * 1024;
  }

#define STAGE_A(T_)                                                         \
  do {                                                                      \
    _Pragma("unroll") for (int s = 0; s < 4; ++s)                           \
        load_lds16(Abase + (size_t)(T_)*BKB + soff[s],                      \
                   As + ((T_)&1) * TILE_BYTES + sdst[s]);                   \
  } while (0)
#define STAGE_B(T_)                                                         \
  do {                                                                      \
    _Pragma("unroll") for (int s = 0; s < 4; ++s)                           \
        load_lds16(Bbase + (size_t)(T_)*BKB + soff[s],                      \
                   Bs + ((T_)&1) * TILE_BYTES + sdst[s]);                   \
  } while (0)

  // swizzled ds_read offsets (chunk = ks*4+lhi, row&7 = l16&7)
  const int axor0 = ((lhi) ^ (l16 & 7)) << 4;
  const int axor1 = ((4 + lhi) ^ (l16 & 7)) << 4;
  const int aoff = wm * 16384 + l16 * 128;  // + mi*2048
  const int boff = wn * 8192 + l16 * 128;   // + nj*2048

  const v4i vz = {0, 0, 0, 0};
  v4i acc[8][4];
#pragma unroll
  for (int i = 0; i < 8; ++i)
#pragma unroll
    for (int j = 0; j < 4; ++j) acc[i][j] = vz;

  v4i a0[8], a1[8], b0[4], b1[4];

#define READ_S0(T_)                                                          \
  do {                                                                       \
    const signed char* Ar_ = As + ((T_)&1) * TILE_BYTES;                     \
    const signed char* Br_ = Bs + ((T_)&1) * TILE_BYTES;                     \
    _Pragma("unroll") for (int nj = 0; nj < 4; ++nj)                         \
        b0[nj] = *(const v4i*)(Br_ + boff + nj * 2048 + axor0);              \
    _Pragma("unroll") for (int mi = 0; mi < 8; ++mi)                         \
        a0[mi] = *(const v4i*)(Ar_ + aoff + mi * 2048 + axor0);              \
  } while (0)
#define READ_S1(T_)                                                          \
  do {                                                                       \
    const signed char* Ar_ = As + ((T_)&1) * TILE_BYTES;                     \
    const signed char* Br_ = Bs + ((T_)&1) * TILE_BYTES;                     \
    _Pragma("unroll") for (int nj = 0; nj < 4; ++nj)                         \
        b1[nj] = *(const v4i*)(Br_ + boff + nj * 2048 + axor1);              \
    _Pragma("unroll") for (int mi = 0; mi < 8; ++mi)                         \
        a1[mi] = *(const v4i*)(Ar_ + aoff + mi * 2048 + axor1);              \
  } while (0)

// 32 independent MFMAs (all distinct acc)
#define KS_BLOCK(A_, B_)                                                     \
  do {                                                                       \
    _Pragma("unroll") for (int mi = 0; mi < 8; ++mi)                         \
      _Pragma("unroll") for (int nj = 0; nj < 4; ++nj)                       \
          acc[mi][nj] = __builtin_amdgcn_mfma_i32_16x16x64_i8(               \
              A_[mi], B_[nj], acc[mi][nj], 0, 0, 0);                         \
  } while (0)

#define LGKM_GATE(n_)                                       \
  do {                                                      \
    asm volatile("s_waitcnt lgkmcnt(" #n_ ")" ::: "memory");\
    __builtin_amdgcn_sched_barrier(0);                      \
  } while (0)

  // prologue: stage tile0, land it, prime S0(0).
  STAGE_A(0); STAGE_B(0);
  asm volatile("s_waitcnt vmcnt(0)" ::: "memory");
  __builtin_amdgcn_s_barrier();
  READ_S0(0);
  __builtin_amdgcn_sched_barrier(0);

  for (int T = 0; T < NT; ++T) {
    // top: S1(T) reads + stage(T+1)
    READ_S1(T);
    __builtin_amdgcn_sched_barrier(0);
    if (T + 1 < NT) { STAGE_A(T + 1); STAGE_B(T + 1); }

    LGKM_GATE(12);  // S0(T) done (12 = S1 reads just issued)
    __builtin_amdgcn_s_setprio(1);
    KS_BLOCK(a0, b0);
    __builtin_amdgcn_s_setprio(0);

    // mid: stage(T+1) landed everywhere -> prefetch S0(T+1)
    asm volatile("s_waitcnt vmcnt(0)" ::: "memory");
    __builtin_amdgcn_s_barrier();
    if (T + 1 < NT) {
      READ_S0(T + 1);
      __builtin_amdgcn_sched_barrier(0);
      LGKM_GATE(12);  // S1(T) done (12 = S0(T+1) just issued)
    } else {
      LGKM_GATE(0);   // last tile: drain S1
    }
    __builtin_amdgcn_s_setprio(1);
    KS_BLOCK(a1, b1);
    __builtin_amdgcn_s_setprio(0);

    __builtin_amdgcn_s_barrier();  // boundary: buf[T] reads done on all waves
  }

  // epilogue: C/D layout col = lane&15, row = (lane>>4)*4 + reg
  float sbv[4];
#pragma unroll
  for (int nj = 0; nj < 4; ++nj) sbv[nj] = sB[n0 + wn * 64 + nj * 16 + l16];
#pragma unroll
  for (int mi = 0; mi < 8; ++mi) {
#pragma unroll
    for (int r = 0; r < 4; ++r) {
      const int row = m0 + wm * 128 + mi * 16 + lhi * 4 + r;
      const float sav = sA[row];
      float* crow = C + (size_t)row * N + (n0 + wn * 64 + l16);
#pragma unroll
      for (int nj = 0; nj < 4; ++nj)
        crow[nj * 16] = (float)acc[mi][nj][r] * sav * sbv[nj];
    }
  }
}

extern "C" void kernel_launch(void* const* d_in, const int* in_sizes, int n_in,
                              void* d_out, int out_size, void* d_ws, size_t ws_size,
                              hipStream_t stream) {
  const float* A = (const float*)d_in[0];
  const float* B = (const float*)d_in[1];
  float* C = (float*)d_out;
  const int K = K_DIM;
  const int M = in_sizes[0] / K;  // 8192
  const int N = in_sizes[1] / K;  // 4096

  signed char* qA = (signed char*)d_ws;
  signed char* qB = qA + (size_t)M * K;
  float* sA = (float*)(qB + (size_t)N * K);
  float* sB = sA + M;

  quant_rows_kernel<<<M, TPB_Q, 0, stream>>>(A, qA, sA);
  quant_rows_kernel<<<N, TPB_Q, 0, stream>>>(B, qB, sB);

  dim3 grid(N / BN, M / BM);
  gemm_i8_kernel<<<grid, 512, 0, stream>>>(qA, qB, sA, sB, C, M, N, K);
}